// Round 16
// baseline (976.067 us; speedup 1.0000x reference)
//
#include <hip/hip_runtime.h>

#define NND 50000
#define NE  800000
#define IND 128
#define HD  256
#define OD  256
#define NH  8
#define ED  64

typedef __attribute__((ext_vector_type(8))) short bf16x8;
typedef __attribute__((ext_vector_type(4))) float f32x4;

__device__ __forceinline__ float bf2f(unsigned short u) {
    union { unsigned int i; float f; } x; x.i = ((unsigned int)u) << 16; return x.f;
}
__device__ __forceinline__ unsigned short f2bf(float f) {
    union { float f; unsigned int i; } x; x.f = f;
    unsigned int u = x.i;
    u += 0x7FFFu + ((u >> 16) & 1u);   // RNE
    return (unsigned short)(u >> 16);
}
// HW packed f32->bf16 (RNE): lo = bf16(a), hi = bf16(b)
__device__ __forceinline__ unsigned int pk2(float a, float b) {
    unsigned int r;
    asm("v_cvt_pk_bf16_f32 %0, %1, %2" : "=v"(r) : "v"(a), "v"(b));
    return r;
}

// ---------------- counting sort by dst ----------------
__global__ void k_hist(const int* __restrict__ eidx, int* __restrict__ cnt) {
    int e = blockIdx.x * 256 + threadIdx.x;
    if (e < NE) atomicAdd(&cnt[eidx[NE + e]], 1);
}

__global__ __launch_bounds__(1024) void k_scan(const int* __restrict__ cnt,
                                               int* __restrict__ head) {
    __shared__ int part[1024];
    const int t = threadIdx.x;
    const int CH = (NND + 1023) / 1024;   // 49
    int base = t * CH;
    int s = 0;
    for (int i = 0; i < CH; ++i) { int idx = base + i; if (idx < NND) s += cnt[idx]; }
    part[t] = s;
    __syncthreads();
    for (int off = 1; off < 1024; off <<= 1) {
        int v = (t >= off) ? part[t - off] : 0;
        __syncthreads();
        part[t] += v;
        __syncthreads();
    }
    int excl = (t == 0) ? 0 : part[t - 1];
    for (int i = 0; i < CH; ++i) {
        int idx = base + i; if (idx >= NND) break;
        head[idx] = excl;
        excl += cnt[idx];
    }
}

__global__ void k_scatter(const int* __restrict__ eidx, int* __restrict__ head,
                          int* __restrict__ perm, int* __restrict__ srcS,
                          int* __restrict__ dstS) {
    int e = blockIdx.x * 256 + threadIdx.x;
    if (e < NE) {
        int s = eidx[e];
        int d = eidx[NE + e];
        int pos = atomicAdd(&head[d], 1);
        perm[pos] = e;
        srcS[pos] = s;
        dstS[pos] = d;
    }
}

// ---------------- weight pack (all 10 in one launch) ----------------
// P[((ct*KS+ks)*64 + l)*8 + j] = bf16( W[(rowoff + k)*N + n] ),
// n = ct*16 + (l&15),  k = ks*32 + (l>>4)*8 + j,  KS = K/32.
__device__ __forceinline__ void pack1(const float* __restrict__ W,
                                      unsigned short* __restrict__ P,
                                      int K, int N, int rowoff, int tid) {
    int j = tid & 7;
    int l = (tid >> 3) & 63;
    int rest = tid >> 9;
    int KS = K >> 5;
    int ks = rest % KS;
    int ct = rest / KS;
    int n = ct * 16 + (l & 15);
    int k = ks * 32 + (l >> 4) * 8 + j;
    P[tid] = f2bf(W[(size_t)(rowoff + k) * N + n]);
}

__global__ void k_packall(const float* __restrict__ Wq1, const float* __restrict__ Wq2,
                          const float* __restrict__ Wk1, const float* __restrict__ Wk2,
                          const float* __restrict__ Wv1, const float* __restrict__ Wv2,
                          unsigned short* __restrict__ Wq1p, unsigned short* __restrict__ Wq2p,
                          unsigned short* __restrict__ WeK,  unsigned short* __restrict__ W2K,
                          unsigned short* __restrict__ WdK,  unsigned short* __restrict__ WsK,
                          unsigned short* __restrict__ WeV,  unsigned short* __restrict__ W2V,
                          unsigned short* __restrict__ WdV,  unsigned short* __restrict__ WsV)
{
    int tid = blockIdx.x * 256 + threadIdx.x;
    int chunk = tid >> 14;
    if      (chunk < 2)   pack1(Wq1, Wq1p, 128, 256, 0,   tid);
    else if (chunk < 6)   pack1(Wq2, Wq2p, 256, 256, 0,   tid - (2 << 14));
    else if (chunk < 7)   pack1(Wk1, WeK,   64, 256, 0,   tid - (6 << 14));
    else if (chunk < 11)  pack1(Wk2, W2K,  256, 256, 0,   tid - (7 << 14));
    else if (chunk < 13)  pack1(Wk1, WdK,  128, 256, 64,  tid - (11 << 14));
    else if (chunk < 15)  pack1(Wk1, WsK,  128, 256, 192, tid - (13 << 14));
    else if (chunk < 16)  pack1(Wv1, WeV,   64, 256, 0,   tid - (15 << 14));
    else if (chunk < 20)  pack1(Wv2, W2V,  256, 256, 0,   tid - (16 << 14));
    else if (chunk < 22)  pack1(Wv1, WdV,  128, 256, 64,  tid - (20 << 14));
    else                  pack1(Wv1, WsV,  128, 256, 192, tid - (22 << 14));
}

// ---------------- MFMA helpers (transposed scheme) ----------------
// D[m=outcol][n=row].  A-slot = packed weights, B-slot = LDS tile rows.
// Lane l: el=l&15, g=l>>4.  D element: m = 64w+16c+4g+r, n = 16i+el.
// Strides 264/136 shorts (33/17 16B-chunks == 1 mod 8): octet covers
// all 32 banks -> conflict-free b128 reads.
__device__ __forceinline__ void zero_acc(f32x4 (&acc)[4][4]) {
    #pragma unroll
    for (int c = 0; c < 4; ++c)
        #pragma unroll
        for (int i = 0; i < 4; ++i)
            #pragma unroll
            for (int r = 0; r < 4; ++r) acc[c][i][r] = 0.f;
}

template<int KS, int STRIDE>
__device__ __forceinline__ void gemmT(const unsigned short* X,
                                      const unsigned short* __restrict__ Wp,
                                      int w, int l, f32x4 (&acc)[4][4]) {
    for (int ks = 0; ks < KS; ++ks) {
        bf16x8 wf[4], xf[4];
        #pragma unroll
        for (int c = 0; c < 4; ++c)
            wf[c] = *(const bf16x8*)(Wp + (((4 * w + c) * KS + ks) * 64 + l) * 8);
        #pragma unroll
        for (int i = 0; i < 4; ++i)
            xf[i] = *(const bf16x8*)(X + (i * 16 + (l & 15)) * STRIDE + ks * 32 + (l >> 4) * 8);
        #pragma unroll
        for (int c = 0; c < 4; ++c)
            #pragma unroll
            for (int i = 0; i < 4; ++i)
                acc[c][i] = __builtin_amdgcn_mfma_f32_16x16x32_bf16(wf[c], xf[i], acc[c][i], 0, 0, 0);
    }
}

// gemm1 with X fragments already in registers (e-tile, K=64 -> KS=2)
__device__ __forceinline__ void gemmR(const bf16x8 (&ef)[2][4],
                                      const unsigned short* __restrict__ Wp,
                                      int w, int l, f32x4 (&acc)[4][4]) {
    #pragma unroll
    for (int ks = 0; ks < 2; ++ks) {
        bf16x8 wf[4];
        #pragma unroll
        for (int c = 0; c < 4; ++c)
            wf[c] = *(const bf16x8*)(Wp + (((4 * w + c) * 2 + ks) * 64 + l) * 8);
        #pragma unroll
        for (int c = 0; c < 4; ++c)
            #pragma unroll
            for (int i = 0; i < 4; ++i)
                acc[c][i] = __builtin_amdgcn_mfma_f32_16x16x32_bf16(wf[c], ef[ks][i], acc[c][i], 0, 0, 0);
    }
}

// ---------------- node kernel: q = MLP_q(h); 4 u-projections ----------------
// All global stores routed through sH then streamed out coalesced (R15).
__global__ __launch_bounds__(256) void k_node(
    const float* __restrict__ h,
    const unsigned short* __restrict__ Wq1p, const float* __restrict__ bq1,
    const unsigned short* __restrict__ Wq2p, const float* __restrict__ bq2,
    unsigned short* __restrict__ qb,
    const unsigned short* __restrict__ WdK, const unsigned short* __restrict__ WsK,
    const unsigned short* __restrict__ WdV, const unsigned short* __restrict__ WsV,
    unsigned short* __restrict__ udK, unsigned short* __restrict__ usK,
    unsigned short* __restrict__ udV, unsigned short* __restrict__ usV)
{
    __shared__ unsigned short sX[64][136];
    __shared__ unsigned short sH[64][264];
    const int t = threadIdx.x, w = t >> 6, l = t & 63;
    const int g = l >> 4, el = l & 15;
    const int m0 = blockIdx.x * 64;

    for (int c = t; c < 2048; c += 256) {
        int row = c >> 5, j = c & 31;
        int node = m0 + row; if (node >= NND) node = NND - 1;
        float4 v = *(const float4*)(h + (size_t)node * IND + j * 4);
        uint2 pk; pk.x = pk2(v.x, v.y); pk.y = pk2(v.z, v.w);
        *(uint2*)(&sX[row][j * 4]) = pk;
    }
    __syncthreads();

    f32x4 acc[4][4];

    // ---- Q MLP ----
    zero_acc(acc);
    gemmT<4, 136>(&sX[0][0], Wq1p, w, l, acc);
    #pragma unroll
    for (int c = 0; c < 4; ++c) {
        int hid0 = 64 * w + 16 * c + 4 * g;
        float4 bv = *(const float4*)(bq1 + hid0);
        #pragma unroll
        for (int i = 0; i < 4; ++i) {
            uint2 pk;
            pk.x = pk2(fmaxf(acc[c][i][0] + bv.x, 0.f), fmaxf(acc[c][i][1] + bv.y, 0.f));
            pk.y = pk2(fmaxf(acc[c][i][2] + bv.z, 0.f), fmaxf(acc[c][i][3] + bv.w, 0.f));
            *(uint2*)(&sH[16 * i + el][hid0]) = pk;
        }
    }
    __syncthreads();

    zero_acc(acc);
    gemmT<8, 264>(&sH[0][0], Wq2p, w, l, acc);
    __syncthreads();   // all waves done reading hidden from sH
    #pragma unroll
    for (int c = 0; c < 4; ++c) {
        int out0 = 64 * w + 16 * c + 4 * g;
        float4 bv = *(const float4*)(bq2 + out0);
        #pragma unroll
        for (int i = 0; i < 4; ++i) {
            uint2 pk;
            pk.x = pk2(acc[c][i][0] + bv.x, acc[c][i][1] + bv.y);
            pk.y = pk2(acc[c][i][2] + bv.z, acc[c][i][3] + bv.w);
            *(uint2*)(&sH[16 * i + el][out0]) = pk;
        }
    }
    __syncthreads();
    // stream sH -> qb coalesced (uint4/lane; wave writes 1 KB contiguous)
    for (int c = t; c < 2048; c += 256) {
        int row = c >> 5, j = c & 31;
        int node = m0 + row;
        if (node < NND)
            *(uint4*)(qb + (size_t)node * OD + j * 8) = *(const uint4*)(&sH[row][j * 8]);
    }
    __syncthreads();

    // ---- 4 u projections (read only sX; epilogue via sH, coalesced out) ----
    const unsigned short* Wps[4]  = {WdK, WsK, WdV, WsV};
    unsigned short*       outs[4] = {udK, usK, udV, usV};
    #pragma unroll 1
    for (int p = 0; p < 4; ++p) {
        zero_acc(acc);
        gemmT<4, 136>(&sX[0][0], Wps[p], w, l, acc);
        #pragma unroll
        for (int c = 0; c < 4; ++c) {
            int hid0 = 64 * w + 16 * c + 4 * g;
            #pragma unroll
            for (int i = 0; i < 4; ++i) {
                uint2 pk;
                pk.x = pk2(acc[c][i][0], acc[c][i][1]);
                pk.y = pk2(acc[c][i][2], acc[c][i][3]);
                *(uint2*)(&sH[16 * i + el][hid0]) = pk;
            }
        }
        __syncthreads();
        unsigned short* outp = outs[p];
        for (int c = t; c < 2048; c += 256) {
            int row = c >> 5, j = c & 31;
            int node = m0 + row;
            if (node < NND)
                *(uint4*)(outp + (size_t)node * HD + j * 8) = *(const uint4*)(&sH[row][j * 8]);
        }
        __syncthreads();
    }
}

// ---------------- fused edge kernel ----------------
// E tile time-shares the H buffer: e staged into H's first 64 cols
// (stride 264 keeps the ==1 mod 8 conflict-free property), fragments
// loaded once into registers (ef), then H is reused for hidden/k/ex*v.
// LDS 46 -> 36 KB => 4 blocks/CU.
struct SmF {
    unsigned short H[64][264];   // 33,792 B  e-staging -> hidden / k / ex*v
    int   Eid[64];
    int   Src[64];
    int   Dst[64];
    float Ex[64][9];             //  2,304 B  (stride 9 floats, coprime with 32)
};

__device__ __forceinline__ void epi_pre(SmF& sm, f32x4 (&acc)[4][4],
                                        const float* __restrict__ b1,
                                        int w, int g, int el) {
    #pragma unroll
    for (int c = 0; c < 4; ++c) {
        int hid0 = 64 * w + 16 * c + 4 * g;
        float4 bv = *(const float4*)(b1 + hid0);
        #pragma unroll
        for (int i = 0; i < 4; ++i) {
            uint2 pk;
            pk.x = pk2(acc[c][i][0] + bv.x, acc[c][i][1] + bv.y);
            pk.y = pk2(acc[c][i][2] + bv.z, acc[c][i][3] + bv.w);
            *(uint2*)(&sm.H[16 * i + el][hid0]) = pk;
        }
    }
}

// H = relu(H + ud[dst] + us[src]) — coalesced row-parallel (R5 form)
__device__ __forceinline__ void elemwise(SmF& sm,
                                         const unsigned short* __restrict__ ud,
                                         const unsigned short* __restrict__ us,
                                         int t) {
    int er = t >> 2;
    const unsigned short* udr = ud + (size_t)sm.Dst[er] * HD;
    const unsigned short* usr = us + (size_t)sm.Src[er] * HD;
    bf16x8 vd[8], vs[8];
    #pragma unroll
    for (int j = 0; j < 8; ++j) {
        int col = (j * 4 + (t & 3)) * 8;
        vd[j] = *(const bf16x8*)(udr + col);
        vs[j] = *(const bf16x8*)(usr + col);
    }
    #pragma unroll
    for (int j = 0; j < 8; ++j) {
        int col = (j * 4 + (t & 3)) * 8;
        bf16x8 hv = *(const bf16x8*)(&sm.H[er][col]);
        float x[8];
        #pragma unroll
        for (int u = 0; u < 8; ++u) {
            x[u] = bf2f((unsigned short)hv[u]) + bf2f((unsigned short)vd[j][u])
                 + bf2f((unsigned short)vs[j][u]);
            x[u] = fmaxf(x[u], 0.f);
        }
        uint4 o;
        o.x = pk2(x[0], x[1]); o.y = pk2(x[2], x[3]);
        o.z = pk2(x[4], x[5]); o.w = pk2(x[6], x[7]);
        *(uint4*)(&sm.H[er][col]) = o;
    }
}

__global__ __launch_bounds__(256, 4) void k_edgeF(
    const float* __restrict__ eattr,
    const int* __restrict__ perm,
    const int* __restrict__ srcS, const int* __restrict__ dstS,
    const unsigned short* __restrict__ WeK, const float* __restrict__ b1K,
    const unsigned short* __restrict__ W2K, const float* __restrict__ b2K,
    const unsigned short* __restrict__ WeV, const float* __restrict__ b1V,
    const unsigned short* __restrict__ W2V, const float* __restrict__ b2V,
    const unsigned short* __restrict__ udK, const unsigned short* __restrict__ usK,
    const unsigned short* __restrict__ udV, const unsigned short* __restrict__ usV,
    const unsigned short* __restrict__ qb,
    float* __restrict__ den, float* __restrict__ outp)
{
    __shared__ SmF sm;
    const int t = threadIdx.x, w = t >> 6, l = t & 63;
    const int g = l >> 4, el = l & 15;
    const int e0 = blockIdx.x * 64;

    if (t < 64) {
        sm.Eid[t] = perm[e0 + t];
        sm.Src[t] = srcS[e0 + t];
        sm.Dst[t] = dstS[e0 + t];
    }
    __syncthreads();
    // stage edge attrs fp32 -> bf16 into H's first 64 cols (stride 264)
    for (int c = t; c < 1024; c += 256) {
        int row = c >> 4, j = c & 15;
        float4 v = *(const float4*)(eattr + (size_t)sm.Eid[row] * ED + j * 4);
        uint2 pk; pk.x = pk2(v.x, v.y); pk.y = pk2(v.z, v.w);
        *(uint2*)(&sm.H[row][j * 4]) = pk;
    }
    __syncthreads();

    // load this thread's 8 e-fragments into registers (shared by K and V gemm1)
    bf16x8 ef[2][4];
    #pragma unroll
    for (int ks = 0; ks < 2; ++ks)
        #pragma unroll
        for (int i = 0; i < 4; ++i)
            ef[ks][i] = *(const bf16x8*)(&sm.H[16 * i + el][ks * 32 + g * 8]);
    __syncthreads();   // all e reads done; H may now be overwritten

    f32x4 acc[4][4];

    // ---- K phase ----
    zero_acc(acc);
    gemmR(ef, WeK, w, l, acc);
    epi_pre(sm, acc, b1K, w, g, el);
    __syncthreads();
    elemwise(sm, udK, usK, t);
    __syncthreads();

    zero_acc(acc);
    gemmT<8, 264>(&sm.H[0][0], W2K, w, l, acc);
    __syncthreads();   // all waves done reading H
    epi_pre(sm, acc, b2K, w, g, el);   // k into H
    __syncthreads();

    // QK dot (coalesced qb: 8 consecutive lanes share one dst row) + den atomics
    {
        const float scale = 0.17677669529663687f;   // 1/sqrt(32)
        for (int p = t; p < 512; p += 256) {
            int er = p >> 3, hh = p & 7;
            int dn = sm.Dst[er];
            const unsigned short* qrow = qb + (size_t)dn * OD + hh * 32;
            float s = 0.f;
            #pragma unroll
            for (int jj = 0; jj < 32; jj += 8) {
                bf16x8 qv = *(const bf16x8*)(qrow + jj);
                bf16x8 kv = *(const bf16x8*)(&sm.H[er][hh * 32 + jj]);
                #pragma unroll
                for (int u = 0; u < 8; ++u)
                    s += bf2f((unsigned short)qv[u]) * bf2f((unsigned short)kv[u]);
            }
            float ex = __expf(s * scale);
            sm.Ex[er][hh] = ex;
            atomicAdd(&den[dn * NH + hh], ex);   // fire-and-forget
        }
    }

    // ---- V phase ----
    zero_acc(acc);
    gemmR(ef, WeV, w, l, acc);     // register operands; no LDS read
    __syncthreads();   // QK readers of H done; Ex visible
    epi_pre(sm, acc, b1V, w, g, el);
    __syncthreads();
    elemwise(sm, udV, usV, t);
    __syncthreads();

    zero_acc(acc);
    gemmT<8, 264>(&sm.H[0][0], W2V, w, l, acc);
    __syncthreads();   // all waves done reading H

    #pragma unroll
    for (int c = 0; c < 4; ++c) {
        int out0 = 64 * w + 16 * c + 4 * g;
        float4 bv = *(const float4*)(b2V + out0);
        int hh = out0 >> 5;
        #pragma unroll
        for (int i = 0; i < 4; ++i) {
            int edge = 16 * i + el;
            float ex = sm.Ex[edge][hh];
            uint2 pk;
            pk.x = pk2((acc[c][i][0] + bv.x) * ex, (acc[c][i][1] + bv.y) * ex);
            pk.y = pk2((acc[c][i][2] + bv.z) * ex, (acc[c][i][3] + bv.w) * ex);
            *(uint2*)(&sm.H[edge][out0]) = pk;
        }
    }
    __syncthreads();

    // column-parallel segment reduction; thread t owns col t (unnormalized)
    {
        float run = 0.f; int prev = sm.Dst[0];
        for (int er = 0; er < 64; ++er) {
            int dn = sm.Dst[er];
            if (dn != prev) {
                atomicAdd(outp + (size_t)prev * OD + t, run);
                run = 0.f; prev = dn;
            }
            run += bf2f(sm.H[er][t]);
        }
        atomicAdd(outp + (size_t)prev * OD + t, run);
    }
}

// final normalize: out[n][c] /= den[n][c>>5]
__global__ void k_norm(float* __restrict__ outp, const float* __restrict__ den) {
    int i = blockIdx.x * 256 + threadIdx.x;   // over NND*OD/4 float4s
    if (i >= NND * OD / 4) return;
    int node = i >> 6;
    int c4 = i & 63;
    int hh = (c4 >> 3);                       // 8 float4 per head
    float d = den[node * NH + hh];
    float inv = d > 0.f ? 1.f / d : 0.f;
    float4 v = *(float4*)(outp + (size_t)i * 4);
    v.x *= inv; v.y *= inv; v.z *= inv; v.w *= inv;
    *(float4*)(outp + (size_t)i * 4) = v;
}

// ---------------- launcher ----------------
extern "C" void kernel_launch(void* const* d_in, const int* in_sizes, int n_in,
                              void* d_out, int out_size, void* d_ws, size_t ws_size,
                              hipStream_t stream)
{
    const float* h   = (const float*)d_in[0];
    const float* e   = (const float*)d_in[1];
    const int*   eid = (const int*)  d_in[2];
    const float* Wk1 = (const float*)d_in[3];
    const float* bk1 = (const float*)d_in[4];
    const float* Wk2 = (const float*)d_in[5];
    const float* bk2 = (const float*)d_in[6];
    const float* Wv1 = (const float*)d_in[7];
    const float* bv1 = (const float*)d_in[8];
    const float* Wv2 = (const float*)d_in[9];
    const float* bv2 = (const float*)d_in[10];
    const float* Wq1 = (const float*)d_in[11];
    const float* bq1 = (const float*)d_in[12];
    const float* Wq2 = (const float*)d_in[13];
    const float* bq2 = (const float*)d_in[14];

    // workspace layout (bytes)
    char* ws = (char*)d_ws;
    size_t off = 0;
    auto take = [&](size_t bytes) { char* p = ws + off; off += bytes; return p; };
    unsigned short* qb   = (unsigned short*)take(25600000);
    unsigned short* udK  = (unsigned short*)take(25600000);
    unsigned short* usK  = (unsigned short*)take(25600000);
    unsigned short* udV  = (unsigned short*)take(25600000);
    unsigned short* usV  = (unsigned short*)take(25600000);
    float*          den  = (float*)         take(1600000);
    int*            cnt  = (int*)           take(200000);
    int*            head = (int*)           take(200000);
    int*            perm = (int*)           take(3200000);
    int*            srcS = (int*)           take(3200000);
    int*            dstS = (int*)           take(3200000);
    unsigned short* Wq1p = (unsigned short*)take(65536);
    unsigned short* Wq2p = (unsigned short*)take(131072);
    unsigned short* WeK  = (unsigned short*)take(32768);
    unsigned short* W2K  = (unsigned short*)take(131072);
    unsigned short* WdK  = (unsigned short*)take(65536);
    unsigned short* WsK  = (unsigned short*)take(65536);
    unsigned short* WeV  = (unsigned short*)take(32768);
    unsigned short* W2V  = (unsigned short*)take(131072);
    unsigned short* WdV  = (unsigned short*)take(65536);
    unsigned short* WsV  = (unsigned short*)take(65536);
    const size_t needed = off;
    if (ws_size < needed) return;   // insufficient scratch -> fail visibly

    hipMemsetAsync(d_out, 0, (size_t)NND * OD * sizeof(float), stream);
    hipMemsetAsync(den, 0, (size_t)NND * NH * sizeof(float), stream);
    hipMemsetAsync(cnt, 0, (size_t)NND * sizeof(int), stream);

    // counting sort of edges by dst
    k_hist<<<(NE + 255) / 256, 256, 0, stream>>>(eid, cnt);
    k_scan<<<1, 1024, 0, stream>>>(cnt, head);
    k_scatter<<<(NE + 255) / 256, 256, 0, stream>>>(eid, head, perm, srcS, dstS);

    // all weight packs in one launch (24 x 16384 elements)
    k_packall<<<(24 << 14) / 256, 256, 0, stream>>>(Wq1, Wq2, Wk1, Wk2, Wv1, Wv2,
                                                    Wq1p, Wq2p, WeK, W2K, WdK, WsK,
                                                    WeV, W2V, WdV, WsV);

    k_node<<<(NND + 63) / 64, 256, 0, stream>>>(h, Wq1p, bq1, Wq2p, bq2, qb,
                                                WdK, WsK, WdV, WsV,
                                                udK, usK, udV, usV);

    k_edgeF<<<NE / 64, 256, 0, stream>>>(e, perm, srcS, dstS,
                                         WeK, bk1, W2K, bk2,
                                         WeV, bv1, W2V, bv2,
                                         udK, usK, udV, usV,
                                         qb, den, (float*)d_out);

    k_norm<<<(NND * OD / 4 + 255) / 256, 256, 0, stream>>>((float*)d_out, den);
}

// Round 17
// 747.210 us; speedup vs baseline: 1.3063x; 1.3063x over previous
//
#include <hip/hip_runtime.h>

#define NND 50000
#define NE  800000
#define IND 128
#define HD  256
#define OD  256
#define NH  8
#define ED  64

typedef __attribute__((ext_vector_type(8))) short bf16x8;
typedef __attribute__((ext_vector_type(4))) float f32x4;

__device__ __forceinline__ float bf2f(unsigned short u) {
    union { unsigned int i; float f; } x; x.i = ((unsigned int)u) << 16; return x.f;
}
__device__ __forceinline__ unsigned short f2bf(float f) {
    union { float f; unsigned int i; } x; x.f = f;
    unsigned int u = x.i;
    u += 0x7FFFu + ((u >> 16) & 1u);   // RNE
    return (unsigned short)(u >> 16);
}
// HW packed f32->bf16 (RNE): lo = bf16(a), hi = bf16(b)
__device__ __forceinline__ unsigned int pk2(float a, float b) {
    unsigned int r;
    asm("v_cvt_pk_bf16_f32 %0, %1, %2" : "=v"(r) : "v"(a), "v"(b));
    return r;
}

// ---------------- counting sort by dst ----------------
__global__ void k_hist(const int* __restrict__ eidx, int* __restrict__ cnt) {
    int e = blockIdx.x * 256 + threadIdx.x;
    if (e < NE) atomicAdd(&cnt[eidx[NE + e]], 1);
}

__global__ __launch_bounds__(1024) void k_scan(const int* __restrict__ cnt,
                                               int* __restrict__ head) {
    __shared__ int part[1024];
    const int t = threadIdx.x;
    const int CH = (NND + 1023) / 1024;   // 49
    int base = t * CH;
    int s = 0;
    for (int i = 0; i < CH; ++i) { int idx = base + i; if (idx < NND) s += cnt[idx]; }
    part[t] = s;
    __syncthreads();
    for (int off = 1; off < 1024; off <<= 1) {
        int v = (t >= off) ? part[t - off] : 0;
        __syncthreads();
        part[t] += v;
        __syncthreads();
    }
    int excl = (t == 0) ? 0 : part[t - 1];
    for (int i = 0; i < CH; ++i) {
        int idx = base + i; if (idx >= NND) break;
        head[idx] = excl;
        excl += cnt[idx];
    }
}

__global__ void k_scatter(const int* __restrict__ eidx, int* __restrict__ head,
                          int* __restrict__ perm, int* __restrict__ srcS,
                          int* __restrict__ dstS) {
    int e = blockIdx.x * 256 + threadIdx.x;
    if (e < NE) {
        int s = eidx[e];
        int d = eidx[NE + e];
        int pos = atomicAdd(&head[d], 1);
        perm[pos] = e;
        srcS[pos] = s;
        dstS[pos] = d;
    }
}

// ---------------- weight pack (all 10 in one launch) ----------------
// P[((ct*KS+ks)*64 + l)*8 + j] = bf16( W[(rowoff + k)*N + n] ),
// n = ct*16 + (l&15),  k = ks*32 + (l>>4)*8 + j,  KS = K/32.
__device__ __forceinline__ void pack1(const float* __restrict__ W,
                                      unsigned short* __restrict__ P,
                                      int K, int N, int rowoff, int tid) {
    int j = tid & 7;
    int l = (tid >> 3) & 63;
    int rest = tid >> 9;
    int KS = K >> 5;
    int ks = rest % KS;
    int ct = rest / KS;
    int n = ct * 16 + (l & 15);
    int k = ks * 32 + (l >> 4) * 8 + j;
    P[tid] = f2bf(W[(size_t)(rowoff + k) * N + n]);
}

__global__ void k_packall(const float* __restrict__ Wq1, const float* __restrict__ Wq2,
                          const float* __restrict__ Wk1, const float* __restrict__ Wk2,
                          const float* __restrict__ Wv1, const float* __restrict__ Wv2,
                          unsigned short* __restrict__ Wq1p, unsigned short* __restrict__ Wq2p,
                          unsigned short* __restrict__ WeK,  unsigned short* __restrict__ W2K,
                          unsigned short* __restrict__ WdK,  unsigned short* __restrict__ WsK,
                          unsigned short* __restrict__ WeV,  unsigned short* __restrict__ W2V,
                          unsigned short* __restrict__ WdV,  unsigned short* __restrict__ WsV)
{
    int tid = blockIdx.x * 256 + threadIdx.x;
    int chunk = tid >> 14;
    if      (chunk < 2)   pack1(Wq1, Wq1p, 128, 256, 0,   tid);
    else if (chunk < 6)   pack1(Wq2, Wq2p, 256, 256, 0,   tid - (2 << 14));
    else if (chunk < 7)   pack1(Wk1, WeK,   64, 256, 0,   tid - (6 << 14));
    else if (chunk < 11)  pack1(Wk2, W2K,  256, 256, 0,   tid - (7 << 14));
    else if (chunk < 13)  pack1(Wk1, WdK,  128, 256, 64,  tid - (11 << 14));
    else if (chunk < 15)  pack1(Wk1, WsK,  128, 256, 192, tid - (13 << 14));
    else if (chunk < 16)  pack1(Wv1, WeV,   64, 256, 0,   tid - (15 << 14));
    else if (chunk < 20)  pack1(Wv2, W2V,  256, 256, 0,   tid - (16 << 14));
    else if (chunk < 22)  pack1(Wv1, WdV,  128, 256, 64,  tid - (20 << 14));
    else                  pack1(Wv1, WsV,  128, 256, 192, tid - (22 << 14));
}

// ---------------- MFMA helpers (transposed scheme) ----------------
// D[m=outcol][n=row].  A-slot = packed weights, B-slot = LDS tile rows.
// Lane l: el=l&15, g=l>>4.  D element: m = 64w+16c+4g+r, n = 16i+el.
// Strides 264/72/136 shorts (33/9/17 16B-chunks == 1 mod 8): octet covers
// all 32 banks -> conflict-free b128 reads.
__device__ __forceinline__ void zero_acc(f32x4 (&acc)[4][4]) {
    #pragma unroll
    for (int c = 0; c < 4; ++c)
        #pragma unroll
        for (int i = 0; i < 4; ++i)
            #pragma unroll
            for (int r = 0; r < 4; ++r) acc[c][i][r] = 0.f;
}

template<int KS, int STRIDE>
__device__ __forceinline__ void gemmT(const unsigned short* X,
                                      const unsigned short* __restrict__ Wp,
                                      int w, int l, f32x4 (&acc)[4][4]) {
    for (int ks = 0; ks < KS; ++ks) {
        bf16x8 wf[4], xf[4];
        #pragma unroll
        for (int c = 0; c < 4; ++c)
            wf[c] = *(const bf16x8*)(Wp + (((4 * w + c) * KS + ks) * 64 + l) * 8);
        #pragma unroll
        for (int i = 0; i < 4; ++i)
            xf[i] = *(const bf16x8*)(X + (i * 16 + (l & 15)) * STRIDE + ks * 32 + (l >> 4) * 8);
        #pragma unroll
        for (int c = 0; c < 4; ++c)
            #pragma unroll
            for (int i = 0; i < 4; ++i)
                acc[c][i] = __builtin_amdgcn_mfma_f32_16x16x32_bf16(wf[c], xf[i], acc[c][i], 0, 0, 0);
    }
}

// ---------------- node kernel: q = MLP_q(h); 4 u-projections ----------------
// All global stores routed through sH then streamed out coalesced
// (uint4/lane; a wave writes 1 KB contiguous) instead of scattered
// 8 B/lane fragment stores.
__global__ __launch_bounds__(256) void k_node(
    const float* __restrict__ h,
    const unsigned short* __restrict__ Wq1p, const float* __restrict__ bq1,
    const unsigned short* __restrict__ Wq2p, const float* __restrict__ bq2,
    unsigned short* __restrict__ qb,
    const unsigned short* __restrict__ WdK, const unsigned short* __restrict__ WsK,
    const unsigned short* __restrict__ WdV, const unsigned short* __restrict__ WsV,
    unsigned short* __restrict__ udK, unsigned short* __restrict__ usK,
    unsigned short* __restrict__ udV, unsigned short* __restrict__ usV)
{
    __shared__ unsigned short sX[64][136];
    __shared__ unsigned short sH[64][264];
    const int t = threadIdx.x, w = t >> 6, l = t & 63;
    const int g = l >> 4, el = l & 15;
    const int m0 = blockIdx.x * 64;

    for (int c = t; c < 2048; c += 256) {
        int row = c >> 5, j = c & 31;
        int node = m0 + row; if (node >= NND) node = NND - 1;
        float4 v = *(const float4*)(h + (size_t)node * IND + j * 4);
        uint2 pk; pk.x = pk2(v.x, v.y); pk.y = pk2(v.z, v.w);
        *(uint2*)(&sX[row][j * 4]) = pk;
    }
    __syncthreads();

    f32x4 acc[4][4];

    // ---- Q MLP ----
    zero_acc(acc);
    gemmT<4, 136>(&sX[0][0], Wq1p, w, l, acc);
    #pragma unroll
    for (int c = 0; c < 4; ++c) {
        int hid0 = 64 * w + 16 * c + 4 * g;
        float4 bv = *(const float4*)(bq1 + hid0);
        #pragma unroll
        for (int i = 0; i < 4; ++i) {
            uint2 pk;
            pk.x = pk2(fmaxf(acc[c][i][0] + bv.x, 0.f), fmaxf(acc[c][i][1] + bv.y, 0.f));
            pk.y = pk2(fmaxf(acc[c][i][2] + bv.z, 0.f), fmaxf(acc[c][i][3] + bv.w, 0.f));
            *(uint2*)(&sH[16 * i + el][hid0]) = pk;
        }
    }
    __syncthreads();

    zero_acc(acc);
    gemmT<8, 264>(&sH[0][0], Wq2p, w, l, acc);
    __syncthreads();   // all waves done reading hidden from sH
    #pragma unroll
    for (int c = 0; c < 4; ++c) {
        int out0 = 64 * w + 16 * c + 4 * g;
        float4 bv = *(const float4*)(bq2 + out0);
        #pragma unroll
        for (int i = 0; i < 4; ++i) {
            uint2 pk;
            pk.x = pk2(acc[c][i][0] + bv.x, acc[c][i][1] + bv.y);
            pk.y = pk2(acc[c][i][2] + bv.z, acc[c][i][3] + bv.w);
            *(uint2*)(&sH[16 * i + el][out0]) = pk;
        }
    }
    __syncthreads();
    // stream sH -> qb coalesced (uint4/lane; wave writes 1 KB contiguous)
    for (int c = t; c < 2048; c += 256) {
        int row = c >> 5, j = c & 31;
        int node = m0 + row;
        if (node < NND)
            *(uint4*)(qb + (size_t)node * OD + j * 8) = *(const uint4*)(&sH[row][j * 8]);
    }
    __syncthreads();

    // ---- 4 u projections (read only sX; epilogue via sH, coalesced out) ----
    const unsigned short* Wps[4]  = {WdK, WsK, WdV, WsV};
    unsigned short*       outs[4] = {udK, usK, udV, usV};
    #pragma unroll 1
    for (int p = 0; p < 4; ++p) {
        zero_acc(acc);
        gemmT<4, 136>(&sX[0][0], Wps[p], w, l, acc);
        #pragma unroll
        for (int c = 0; c < 4; ++c) {
            int hid0 = 64 * w + 16 * c + 4 * g;
            #pragma unroll
            for (int i = 0; i < 4; ++i) {
                uint2 pk;
                pk.x = pk2(acc[c][i][0], acc[c][i][1]);
                pk.y = pk2(acc[c][i][2], acc[c][i][3]);
                *(uint2*)(&sH[16 * i + el][hid0]) = pk;
            }
        }
        __syncthreads();
        unsigned short* outp = outs[p];
        for (int c = t; c < 2048; c += 256) {
            int row = c >> 5, j = c & 31;
            int node = m0 + row;
            if (node < NND)
                *(uint4*)(outp + (size_t)node * HD + j * 8) = *(const uint4*)(&sH[row][j * 8]);
        }
        __syncthreads();
    }
}

// ---------------- fused edge kernel (R9/R14 verified best) ----------------
struct SmF {
    unsigned short E[64][72];    //  9,216 B  e-tile (9 chunks == 1 mod 8)
    unsigned short H[64][264];   // 33,792 B  hidden / k / ex*v (33 chunks == 1 mod 8)
    int   Eid[64];
    int   Src[64];
    int   Dst[64];
    float Ex[64][9];             //  2,304 B  (stride 9 floats, coprime with 32)
};

__device__ __forceinline__ void epi_pre(SmF& sm, f32x4 (&acc)[4][4],
                                        const float* __restrict__ b1,
                                        int w, int g, int el) {
    #pragma unroll
    for (int c = 0; c < 4; ++c) {
        int hid0 = 64 * w + 16 * c + 4 * g;
        float4 bv = *(const float4*)(b1 + hid0);
        #pragma unroll
        for (int i = 0; i < 4; ++i) {
            uint2 pk;
            pk.x = pk2(acc[c][i][0] + bv.x, acc[c][i][1] + bv.y);
            pk.y = pk2(acc[c][i][2] + bv.z, acc[c][i][3] + bv.w);
            *(uint2*)(&sm.H[16 * i + el][hid0]) = pk;
        }
    }
}

// H = relu(H + ud[dst] + us[src]) — coalesced row-parallel (R5 form)
__device__ __forceinline__ void elemwise(SmF& sm,
                                         const unsigned short* __restrict__ ud,
                                         const unsigned short* __restrict__ us,
                                         int t) {
    int er = t >> 2;
    const unsigned short* udr = ud + (size_t)sm.Dst[er] * HD;
    const unsigned short* usr = us + (size_t)sm.Src[er] * HD;
    bf16x8 vd[8], vs[8];
    #pragma unroll
    for (int j = 0; j < 8; ++j) {
        int col = (j * 4 + (t & 3)) * 8;
        vd[j] = *(const bf16x8*)(udr + col);
        vs[j] = *(const bf16x8*)(usr + col);
    }
    #pragma unroll
    for (int j = 0; j < 8; ++j) {
        int col = (j * 4 + (t & 3)) * 8;
        bf16x8 hv = *(const bf16x8*)(&sm.H[er][col]);
        float x[8];
        #pragma unroll
        for (int u = 0; u < 8; ++u) {
            x[u] = bf2f((unsigned short)hv[u]) + bf2f((unsigned short)vd[j][u])
                 + bf2f((unsigned short)vs[j][u]);
            x[u] = fmaxf(x[u], 0.f);
        }
        uint4 o;
        o.x = pk2(x[0], x[1]); o.y = pk2(x[2], x[3]);
        o.z = pk2(x[4], x[5]); o.w = pk2(x[6], x[7]);
        *(uint4*)(&sm.H[er][col]) = o;
    }
}

__global__ __launch_bounds__(256, 3) void k_edgeF(
    const float* __restrict__ eattr,
    const int* __restrict__ perm,
    const int* __restrict__ srcS, const int* __restrict__ dstS,
    const unsigned short* __restrict__ WeK, const float* __restrict__ b1K,
    const unsigned short* __restrict__ W2K, const float* __restrict__ b2K,
    const unsigned short* __restrict__ WeV, const float* __restrict__ b1V,
    const unsigned short* __restrict__ W2V, const float* __restrict__ b2V,
    const unsigned short* __restrict__ udK, const unsigned short* __restrict__ usK,
    const unsigned short* __restrict__ udV, const unsigned short* __restrict__ usV,
    const unsigned short* __restrict__ qb,
    float* __restrict__ den, float* __restrict__ outp)
{
    __shared__ SmF sm;
    const int t = threadIdx.x, w = t >> 6, l = t & 63;
    const int g = l >> 4, el = l & 15;
    const int e0 = blockIdx.x * 64;

    if (t < 64) {
        sm.Eid[t] = perm[e0 + t];
        sm.Src[t] = srcS[e0 + t];
        sm.Dst[t] = dstS[e0 + t];
    }
    __syncthreads();
    // gather edge attrs fp32 -> bf16 (16 threads per row, 64 B segments)
    for (int c = t; c < 1024; c += 256) {
        int row = c >> 4, j = c & 15;
        float4 v = *(const float4*)(eattr + (size_t)sm.Eid[row] * ED + j * 4);
        uint2 pk; pk.x = pk2(v.x, v.y); pk.y = pk2(v.z, v.w);
        *(uint2*)(&sm.E[row][j * 4]) = pk;
    }
    __syncthreads();

    f32x4 acc[4][4];

    // ---- K phase ----
    zero_acc(acc);
    gemmT<2, 72>(&sm.E[0][0], WeK, w, l, acc);
    epi_pre(sm, acc, b1K, w, g, el);
    __syncthreads();
    elemwise(sm, udK, usK, t);
    __syncthreads();

    zero_acc(acc);
    gemmT<8, 264>(&sm.H[0][0], W2K, w, l, acc);
    __syncthreads();   // all waves done reading H
    epi_pre(sm, acc, b2K, w, g, el);   // k into H
    __syncthreads();

    // QK dot (coalesced qb: 8 consecutive lanes share one dst row) + den atomics
    {
        const float scale = 0.17677669529663687f;   // 1/sqrt(32)
        for (int p = t; p < 512; p += 256) {
            int er = p >> 3, hh = p & 7;
            int dn = sm.Dst[er];
            const unsigned short* qrow = qb + (size_t)dn * OD + hh * 32;
            float s = 0.f;
            #pragma unroll
            for (int jj = 0; jj < 32; jj += 8) {
                bf16x8 qv = *(const bf16x8*)(qrow + jj);
                bf16x8 kv = *(const bf16x8*)(&sm.H[er][hh * 32 + jj]);
                #pragma unroll
                for (int u = 0; u < 8; ++u)
                    s += bf2f((unsigned short)qv[u]) * bf2f((unsigned short)kv[u]);
            }
            float ex = __expf(s * scale);
            sm.Ex[er][hh] = ex;
            atomicAdd(&den[dn * NH + hh], ex);   // fire-and-forget
        }
    }

    // ---- V phase ----
    zero_acc(acc);
    gemmT<2, 72>(&sm.E[0][0], WeV, w, l, acc);   // E untouched; no barrier needed yet
    __syncthreads();   // QK readers of H done; Ex visible
    epi_pre(sm, acc, b1V, w, g, el);
    __syncthreads();
    elemwise(sm, udV, usV, t);
    __syncthreads();

    zero_acc(acc);
    gemmT<8, 264>(&sm.H[0][0], W2V, w, l, acc);
    __syncthreads();   // all waves done reading H

    #pragma unroll
    for (int c = 0; c < 4; ++c) {
        int out0 = 64 * w + 16 * c + 4 * g;
        float4 bv = *(const float4*)(b2V + out0);
        int hh = out0 >> 5;
        #pragma unroll
        for (int i = 0; i < 4; ++i) {
            int edge = 16 * i + el;
            float ex = sm.Ex[edge][hh];
            uint2 pk;
            pk.x = pk2((acc[c][i][0] + bv.x) * ex, (acc[c][i][1] + bv.y) * ex);
            pk.y = pk2((acc[c][i][2] + bv.z) * ex, (acc[c][i][3] + bv.w) * ex);
            *(uint2*)(&sm.H[edge][out0]) = pk;
        }
    }
    __syncthreads();

    // column-parallel segment reduction; thread t owns col t (unnormalized)
    {
        float run = 0.f; int prev = sm.Dst[0];
        for (int er = 0; er < 64; ++er) {
            int dn = sm.Dst[er];
            if (dn != prev) {
                atomicAdd(outp + (size_t)prev * OD + t, run);
                run = 0.f; prev = dn;
            }
            run += bf2f(sm.H[er][t]);
        }
        atomicAdd(outp + (size_t)prev * OD + t, run);
    }
}

// final normalize: out[n][c] /= den[n][c>>5]
__global__ void k_norm(float* __restrict__ outp, const float* __restrict__ den) {
    int i = blockIdx.x * 256 + threadIdx.x;   // over NND*OD/4 float4s
    if (i >= NND * OD / 4) return;
    int node = i >> 6;
    int c4 = i & 63;
    int hh = (c4 >> 3);                       // 8 float4 per head
    float d = den[node * NH + hh];
    float inv = d > 0.f ? 1.f / d : 0.f;
    float4 v = *(float4*)(outp + (size_t)i * 4);
    v.x *= inv; v.y *= inv; v.z *= inv; v.w *= inv;
    *(float4*)(outp + (size_t)i * 4) = v;
}

// ---------------- launcher ----------------
extern "C" void kernel_launch(void* const* d_in, const int* in_sizes, int n_in,
                              void* d_out, int out_size, void* d_ws, size_t ws_size,
                              hipStream_t stream)
{
    const float* h   = (const float*)d_in[0];
    const float* e   = (const float*)d_in[1];
    const int*   eid = (const int*)  d_in[2];
    const float* Wk1 = (const float*)d_in[3];
    const float* bk1 = (const float*)d_in[4];
    const float* Wk2 = (const float*)d_in[5];
    const float* bk2 = (const float*)d_in[6];
    const float* Wv1 = (const float*)d_in[7];
    const float* bv1 = (const float*)d_in[8];
    const float* Wv2 = (const float*)d_in[9];
    const float* bv2 = (const float*)d_in[10];
    const float* Wq1 = (const float*)d_in[11];
    const float* bq1 = (const float*)d_in[12];
    const float* Wq2 = (const float*)d_in[13];
    const float* bq2 = (const float*)d_in[14];

    // workspace layout (bytes)
    char* ws = (char*)d_ws;
    size_t off = 0;
    auto take = [&](size_t bytes) { char* p = ws + off; off += bytes; return p; };
    unsigned short* qb   = (unsigned short*)take(25600000);
    unsigned short* udK  = (unsigned short*)take(25600000);
    unsigned short* usK  = (unsigned short*)take(25600000);
    unsigned short* udV  = (unsigned short*)take(25600000);
    unsigned short* usV  = (unsigned short*)take(25600000);
    float*          den  = (float*)         take(1600000);
    int*            cnt  = (int*)           take(200000);
    int*            head = (int*)           take(200000);
    int*            perm = (int*)           take(3200000);
    int*            srcS = (int*)           take(3200000);
    int*            dstS = (int*)           take(3200000);
    unsigned short* Wq1p = (unsigned short*)take(65536);
    unsigned short* Wq2p = (unsigned short*)take(131072);
    unsigned short* WeK  = (unsigned short*)take(32768);
    unsigned short* W2K  = (unsigned short*)take(131072);
    unsigned short* WdK  = (unsigned short*)take(65536);
    unsigned short* WsK  = (unsigned short*)take(65536);
    unsigned short* WeV  = (unsigned short*)take(32768);
    unsigned short* W2V  = (unsigned short*)take(131072);
    unsigned short* WdV  = (unsigned short*)take(65536);
    unsigned short* WsV  = (unsigned short*)take(65536);
    const size_t needed = off;
    if (ws_size < needed) return;   // insufficient scratch -> fail visibly

    hipMemsetAsync(d_out, 0, (size_t)NND * OD * sizeof(float), stream);
    hipMemsetAsync(den, 0, (size_t)NND * NH * sizeof(float), stream);
    hipMemsetAsync(cnt, 0, (size_t)NND * sizeof(int), stream);

    // counting sort of edges by dst
    k_hist<<<(NE + 255) / 256, 256, 0, stream>>>(eid, cnt);
    k_scan<<<1, 1024, 0, stream>>>(cnt, head);
    k_scatter<<<(NE + 255) / 256, 256, 0, stream>>>(eid, head, perm, srcS, dstS);

    // all weight packs in one launch (24 x 16384 elements)
    k_packall<<<(24 << 14) / 256, 256, 0, stream>>>(Wq1, Wq2, Wk1, Wk2, Wv1, Wv2,
                                                    Wq1p, Wq2p, WeK, W2K, WdK, WsK,
                                                    WeV, W2V, WdV, WsV);

    k_node<<<(NND + 63) / 64, 256, 0, stream>>>(h, Wq1p, bq1, Wq2p, bq2, qb,
                                                WdK, WsK, WdV, WsV,
                                                udK, usK, udV, usV);

    k_edgeF<<<NE / 64, 256, 0, stream>>>(e, perm, srcS, dstS,
                                         WeK, bk1, W2K, bk2,
                                         WeV, bv1, W2V, bv2,
                                         udK, usK, udV, usV,
                                         qb, den, (float*)d_out);

    k_norm<<<(NND * OD / 4 + 255) / 256, 256, 0, stream>>>((float*)d_out, den);
}